// Round 1
// baseline (422.983 us; speedup 1.0000x reference)
//
#include <hip/hip_runtime.h>
#include <math.h>

#define NN 100000
#define NE 200000
#define HD 128
#define CAPN 4096
#define CAPB 256
#define NGROUP 21
#define NBUCK (NGROUP * 64)
#define AP 136   // bf16 LDS row pitch (shorts)
#define MP 132   // f32 LDS msg row pitch
#define NTHR 256

typedef short bf16x8 __attribute__((ext_vector_type(8)));
typedef float f32x4 __attribute__((ext_vector_type(4)));

// workspace byte offsets
#define OFF_NCNT   0                // 21 ints
#define OFF_BECNT  256              // 1344 ints (live edges per (group,dst-tile) bucket)
#define OFF_ZCNT   5632             // 21*4096*8 ints (zero-edge counts per dst,src-gate)
#define MEMSET_BYTES 2758144        // covers ncnt+becnt+zcnt
#define OFF_HSTYPE 2758144          // 6*128 f32
#define OFF_HSW1   2761216          // 3*6*128 f32
#define OFF_ZTAB   2770432          // 3*6*128 f32 (msg of a zero-hf src, per gi,src-gate)
#define OFF_WBMLP  2779648          // 3*3*16384 bf16 swizzled B-frags
#define OFF_WBIH   3074560          // 3*49152 bf16 swizzled B-frags
#define OFF_NLIST  3369472          // 21*4096 ints
#define OFF_NSLOT  3713536          // NN ints
#define OFF_EPK    4113536          // 1344*256 ints: src | gate<<17 | localslot<<23

#define SWTOT (3 * 3 * 16384 + 3 * 49152)

__device__ __forceinline__ int gi_of(int g) {
    return (g == 3) ? 0 : (g == 2) ? 1 : (g == 5) ? 2 : -1;
}

__device__ __forceinline__ unsigned short f2bf(float f) {
    unsigned int u = __float_as_uint(f);
    u += 0x7FFF + ((u >> 16) & 1);   // RNE
    return (unsigned short)(u >> 16);
}

// ---------------------------------------------------------------------------
// prep1: block 0 -> hs_type + hsW1; blocks 1..18 -> ztab rows (self-contained);
// blocks 19+ -> weight swizzle + group_nodes (LDS-aggregated).
// ---------------------------------------------------------------------------
__global__ __launch_bounds__(NTHR) void prep1_kernel(
    const int* __restrict__ gate, const int* __restrict__ lvl,
    const float* __restrict__ Ws, const float* __restrict__ Wt,
    const float* __restrict__ hs_W, const float* __restrict__ hs_b,
    const float* __restrict__ w1, const float* __restrict__ b1,
    const float* __restrict__ w2, const float* __restrict__ b2,
    const float* __restrict__ w3, const float* __restrict__ b3,
    const float* __restrict__ wih,
    float* __restrict__ hs_type, float* __restrict__ hsW1,
    float* __restrict__ ztab,
    unsigned short* __restrict__ wbmlp, unsigned short* __restrict__ wbih,
    int* __restrict__ ncnt, int* __restrict__ nlist, int* __restrict__ nslot) {
    __shared__ float lht[6 * HD];
    __shared__ float s0[HD], s1[HD], s2[HD];
    __shared__ int lcnt[NGROUP], lbase[NGROUP];
    const int bid = blockIdx.x, tid = threadIdx.x;

    if (bid == 0) {
        for (int idx = tid; idx < 6 * HD; idx += NTHR) {
            int t = idx >> 7, c = idx & 127;
            float acc = hs_b[c];
            for (int k = 0; k < HD; k++) acc = fmaf(Ws[t * HD + k], hs_W[k * HD + c], acc);
            for (int k = 0; k < HD; k++) acc = fmaf(Wt[t * HD + k], hs_W[(HD + k) * HD + c], acc);
            lht[idx] = acc;
            hs_type[idx] = acc;
        }
        __syncthreads();
        for (int idx = tid; idx < 3 * 6 * HD; idx += NTHR) {
            int gi = idx / (6 * HD);
            int t = (idx >> 7) % 6;
            int c = idx & 127;
            const float* w = w1 + gi * (2 * HD * HD);  // top half rows 0..127
            float acc = 0.f;
            for (int k = 0; k < HD; k++) acc = fmaf(lht[t * HD + k], w[k * HD + c], acc);
            hsW1[idx] = acc;
        }
    } else if (bid <= 18) {
        // ztab[gi][t] = MLP_gi([hs_type[t], 0]) — fp32, self-contained
        int gi = (bid - 1) / 6, t = (bid - 1) % 6;
        int c = tid;
        if (c < HD) {
            float acc = hs_b[c];
            for (int k = 0; k < HD; k++) acc = fmaf(Ws[t * HD + k], hs_W[k * HD + c], acc);
            for (int k = 0; k < HD; k++) acc = fmaf(Wt[t * HD + k], hs_W[(HD + k) * HD + c], acc);
            s0[c] = acc;
        }
        __syncthreads();
        if (c < HD) {
            const float* w = w1 + gi * (2 * HD * HD);  // top half
            float acc = b1[gi * HD + c];
            for (int k = 0; k < HD; k++) acc = fmaf(s0[k], w[k * HD + c], acc);
            s1[c] = fmaxf(acc, 0.f);
        }
        __syncthreads();
        if (c < HD) {
            const float* w = w2 + gi * (HD * HD);
            float acc = b2[gi * HD + c];
            for (int k = 0; k < HD; k++) acc = fmaf(s1[k], w[k * HD + c], acc);
            s2[c] = fmaxf(acc, 0.f);
        }
        __syncthreads();
        if (c < HD) {
            const float* w = w3 + gi * (HD * HD);
            float acc = b3[gi * HD + c];
            for (int k = 0; k < HD; k++) acc = fmaf(s2[k], w[k * HD + c], acc);
            ztab[(gi * 6 + t) * HD + c] = acc;
        }
    } else {
        const int nb = gridDim.x - 19;          // worker blocks
        const int wb = bid - 19;
        // weight swizzle into MFMA B-fragment layout
        for (int id = wb * NTHR + tid; id < SWTOT; id += nb * NTHR) {
            if (id < 3 * 3 * 16384) {
                int gi = id / 49152;
                int rem = id % 49152;
                int layer = rem / 16384;
                int e = rem % 16384;
                int k = e >> 7, n = e & 127;
                float v;
                if (layer == 0)      v = w1[gi * (2 * HD * HD) + (HD + k) * HD + n];
                else if (layer == 1) v = w2[gi * (HD * HD) + k * HD + n];
                else                 v = w3[gi * (HD * HD) + k * HD + n];
                int nt = n >> 4, kc = k >> 5, kq = (k >> 3) & 3, j = k & 7;
                int L = (kq << 4) | (n & 15);
                wbmlp[(size_t)(gi * 3 + layer) * 16384 + ((nt * 4 + kc) * 64 + L) * 8 + j] = f2bf(v);
            } else {
                int id2 = id - 3 * 3 * 16384;
                int gi = id2 / 49152;
                int e = id2 % 49152;
                int k = e / 384, n = e % 384;             // B[k][n] = wih[n][k]
                float v = wih[gi * (384 * HD) + n * HD + k];
                int nt = n >> 4, kc = k >> 5, kq = (k >> 3) & 3, j = k & 7;
                int L = (kq << 4) | (n & 15);
                wbih[(size_t)gi * 49152 + ((nt * 4 + kc) * 64 + L) * 8 + j] = f2bf(v);
            }
        }
        // group_nodes (LDS-aggregated)
        for (int base = wb * NTHR; base < NN; base += nb * NTHR) {
            if (tid < NGROUP) lcnt[tid] = 0;
            __syncthreads();
            int i = base + tid;
            int glob = -1, local = 0;
            if (i < NN) {
                int gi = gi_of(gate[i]);
                int l = lvl[i];
                if (gi >= 0 && l >= 1) {
                    glob = (l - 1) * 3 + gi;
                    local = atomicAdd(&lcnt[glob], 1);
                }
            }
            __syncthreads();
            if (tid < NGROUP) {
                int cc = lcnt[tid];
                lbase[tid] = cc ? atomicAdd(&ncnt[tid], cc) : 0;
            }
            __syncthreads();
            if (glob >= 0) {
                int slot = lbase[glob] + local;
                if (slot < CAPN) {
                    nlist[glob * CAPN + slot] = i;
                    nslot[i] = slot;
                }
            }
            __syncthreads();
        }
    }
}

// ---------------------------------------------------------------------------
// prep2: scatter hs / zero hf + classify edges.
// Live edges -> per-(group, dst-tile) bucket, packed src|gate|localslot.
// Zero-hf edges -> one int atomicAdd into zcnt[(glob,dslot,src_gate)].
// ---------------------------------------------------------------------------
__global__ __launch_bounds__(NTHR) void prep2_kernel(
    const int* __restrict__ gate, const int* __restrict__ lvl,
    const int* __restrict__ ei, const int* __restrict__ nslot,
    const float* __restrict__ hs_type, float* __restrict__ out,
    int* __restrict__ becnt, int* __restrict__ epk,
    int* __restrict__ zcnt) {
    const int stride = gridDim.x * NTHR;
    const int tid0 = blockIdx.x * NTHR + threadIdx.x;

    const float4* ht4 = (const float4*)hs_type;
    float4* o4 = (float4*)out;
    for (int idx = tid0; idx < NN * 32; idx += stride) {
        int i = idx >> 5, q = idx & 31;
        o4[idx] = ht4[gate[i] * 32 + q];
        o4[(size_t)NN * 32 + idx] = make_float4(0.f, 0.f, 0.f, 0.f);
    }

    for (int e = tid0; e < NE; e += stride) {
        int d = ei[NE + e];
        int gd = gi_of(gate[d]);
        int ld = lvl[d];
        if (gd < 0 || ld < 1) continue;
        int g = (ld - 1) * 3 + gd;
        int s = ei[e];
        int dsl = nslot[d];
        int gs = gate[s], ls = lvl[s];
        bool live = (gi_of(gs) >= 0) && (ls >= 1) && (ls < ld);
        if (live) {
            int bucket = g * 64 + (dsl >> 6);
            int slot = atomicAdd(&becnt[bucket], 1);
            if (slot < CAPB)
                epk[(size_t)bucket * CAPB + slot] = s | (gs << 17) | ((dsl & 63) << 23);
        } else {
            atomicAdd(&zcnt[((size_t)g * CAPN + dsl) * 8 + gs], 1);
        }
    }
}

// ---------------------------------------------------------------------------
// level_kernel: fused msg-MLP + GRU for one level. grid = 3 x 64 dst-tiles.
// Per block: fold ztab (zero-hf edges) into LDS f32 msg accumulator, run the
// 3-layer MFMA MLP over this tile's live-edge bucket with LDS-atomic scatter,
// then GRU via MFMA, write hf. One kernel per level instead of two; no global
// msg buffer.
// ---------------------------------------------------------------------------
__global__ __launch_bounds__(NTHR) void level_kernel(
    int level, const int* __restrict__ ncnt, const int* __restrict__ nlist,
    const int* __restrict__ becnt, const int* __restrict__ epk,
    const int* __restrict__ zcnt, const float* __restrict__ ztab,
    const float* __restrict__ hf_in,
    const unsigned short* __restrict__ wbmlp, const unsigned short* __restrict__ wbih,
    const float* __restrict__ b1, const float* __restrict__ b2,
    const float* __restrict__ b3, const float* __restrict__ hsW1,
    const float* __restrict__ bih, const float* __restrict__ bhh,
    float* __restrict__ out) {
    __shared__ unsigned short A[64 * AP];   // 17408 B
    __shared__ float msgf[64 * MP];         // 33792 B
    __shared__ float hsw[6 * 132];          // 3168 B
    __shared__ int zs[64 * 8];              // 2048 B

    const int gi = blockIdx.x >> 6;
    const int tilei = blockIdx.x & 63;
    const int glob = (level - 1) * 3 + gi;
    int cnt = ncnt[glob]; if (cnt > CAPN) cnt = CAPN;
    const int tile = tilei * 64;
    if (tile >= cnt) return;
    const int nv = min(64, cnt - tile);

    const int tid = threadIdx.x;
    const int ln = tid & 63, wv = tid >> 6;
    const int lc = ln & 15, quad = ln >> 4;
    const int rbase = wv * 16;

    // stage zcnt for this tile's 64 dst slots + hsW1 rows
    for (int i = tid; i < 64 * 8; i += NTHR)
        zs[i] = zcnt[((size_t)(glob * CAPN + tile)) * 8 + i];
    for (int i = tid; i < 6 * 132; i += NTHR) {
        int t = i / 132, c = i % 132;
        hsw[i] = (c < HD) ? hsW1[(gi * 6 + t) * HD + c] : 0.f;
    }
    __syncthreads();

    // init msg accumulator with zero-hf edge contributions: Sum_t zs[t]*ztab[gi][t]
    const f32x4* zt4 = (const f32x4*)ztab;
    for (int id = tid; id < 64 * 32; id += NTHR) {
        int row = id >> 5, lane = id & 31;
        f32x4 acc = {0.f, 0.f, 0.f, 0.f};
#pragma unroll
        for (int t = 0; t < 6; t++) {
            int ct = zs[row * 8 + t];
            if (ct) {
                float f = (float)ct;
                f32x4 z = zt4[(gi * 6 + t) * 32 + lane];
                acc.x = fmaf(f, z.x, acc.x);
                acc.y = fmaf(f, z.y, acc.y);
                acc.z = fmaf(f, z.z, acc.z);
                acc.w = fmaf(f, z.w, acc.w);
            }
        }
        *(f32x4*)&msgf[row * MP + lane * 4] = acc;
    }
    __syncthreads();

    // ---- live-edge MLP phase (wave-local 16-row bands per 64-edge chunk) ----
    const int bucket = glob * 64 + tilei;
    int ecb = becnt[bucket]; if (ecb > CAPB) ecb = CAPB;
    if (ecb) {
        const int* ep = epk + (size_t)bucket * CAPB;
        const unsigned short* WB = wbmlp + (size_t)gi * 3 * 16384;
        float b1v[8], b2v[8], b3v[8];
#pragma unroll
        for (int nt = 0; nt < 8; nt++) {
            b1v[nt] = b1[gi * HD + nt * 16 + lc];
            b2v[nt] = b2[gi * HD + nt * 16 + lc];
            b3v[nt] = b3[gi * HD + nt * 16 + lc];
        }
        for (int c0 = 0; c0 < ecb; c0 += 64) {
            int ne = min(64, ecb - c0);
            // wave-local staging of hf[src] (bf16)
            {
                int row = rbase + (ln >> 2), q = ln & 3;
                unsigned int* Au = (unsigned int*)A;
                int base = (row * AP + q * 32) >> 1;
                if (row < ne) {
                    int s = ep[c0 + row] & 0x1FFFF;
                    const float4* src4 = (const float4*)(hf_in + (size_t)s * HD + q * 32);
#pragma unroll
                    for (int i = 0; i < 8; i++) {
                        float4 v = src4[i];
                        Au[base + i * 2]     = f2bf(v.x) | ((unsigned int)f2bf(v.y) << 16);
                        Au[base + i * 2 + 1] = f2bf(v.z) | ((unsigned int)f2bf(v.w) << 16);
                    }
                } else {
#pragma unroll
                    for (int i = 0; i < 16; i++) Au[base + i] = 0u;
                }
            }
            int sg = 0, lo = 0;
            if (ln < 16) {
                int r2 = rbase + ln;
                if (r2 < ne) {
                    int p = ep[c0 + r2];
                    sg = (p >> 17) & 7;
                    lo = (p >> 23) & 63;
                }
            }

            // layer 1: relu(hsW1[gate_src] + hf@W1bot + b1), in-place
            {
                bf16x8 af[4];
#pragma unroll
                for (int kc = 0; kc < 4; kc++)
                    af[kc] = *(bf16x8*)&A[(rbase + lc) * AP + kc * 32 + quad * 8];
                for (int nt = 0; nt < 8; nt++) {
                    f32x4 acc = {0.f, 0.f, 0.f, 0.f};
#pragma unroll
                    for (int kc = 0; kc < 4; kc++) {
                        bf16x8 bf = *(const bf16x8*)&WB[((nt * 4 + kc) * 64 + ln) * 8];
                        acc = __builtin_amdgcn_mfma_f32_16x16x32_bf16(af[kc], bf, acc, 0, 0, 0);
                    }
#pragma unroll
                    for (int r = 0; r < 4; r++) {
                        int row = rbase + quad * 4 + r;
                        int sgr = __shfl(sg, quad * 4 + r);
                        float v = acc[r] + hsw[sgr * 132 + nt * 16 + lc] + b1v[nt];
                        A[row * AP + nt * 16 + lc] = f2bf(fmaxf(v, 0.f));
                    }
                }
            }
            // layer 2
            {
                bf16x8 af[4];
#pragma unroll
                for (int kc = 0; kc < 4; kc++)
                    af[kc] = *(bf16x8*)&A[(rbase + lc) * AP + kc * 32 + quad * 8];
                for (int nt = 0; nt < 8; nt++) {
                    f32x4 acc = {0.f, 0.f, 0.f, 0.f};
#pragma unroll
                    for (int kc = 0; kc < 4; kc++) {
                        bf16x8 bf = *(const bf16x8*)&WB[16384 + ((nt * 4 + kc) * 64 + ln) * 8];
                        acc = __builtin_amdgcn_mfma_f32_16x16x32_bf16(af[kc], bf, acc, 0, 0, 0);
                    }
#pragma unroll
                    for (int r = 0; r < 4; r++) {
                        int row = rbase + quad * 4 + r;
                        A[row * AP + nt * 16 + lc] = f2bf(fmaxf(acc[r] + b2v[nt], 0.f));
                    }
                }
            }
            // layer 3 + LDS scatter-add into msgf
            {
                bf16x8 af[4];
#pragma unroll
                for (int kc = 0; kc < 4; kc++)
                    af[kc] = *(bf16x8*)&A[(rbase + lc) * AP + kc * 32 + quad * 8];
                for (int nt = 0; nt < 8; nt++) {
                    f32x4 acc = {0.f, 0.f, 0.f, 0.f};
#pragma unroll
                    for (int kc = 0; kc < 4; kc++) {
                        bf16x8 bf = *(const bf16x8*)&WB[2 * 16384 + ((nt * 4 + kc) * 64 + ln) * 8];
                        acc = __builtin_amdgcn_mfma_f32_16x16x32_bf16(af[kc], bf, acc, 0, 0, 0);
                    }
#pragma unroll
                    for (int r = 0; r < 4; r++) {
                        int row = rbase + quad * 4 + r;
                        if (row < ne) {
                            int lr = __shfl(lo, quad * 4 + r);
                            atomicAdd(&msgf[lr * MP + nt * 16 + lc], acc[r] + b3v[nt]);
                        }
                    }
                }
            }
        }
    }
    __syncthreads();

    // ---- GRU phase: gin = msg @ wih.T + bih ; gh = bhh (h_old == 0) ----
    int nd = -1;
    if (ln < 16) {
        int r2 = rbase + ln;
        nd = (r2 < nv) ? nlist[glob * CAPN + tile + r2] : -1;
    }
    bf16x8 af[4];
#pragma unroll
    for (int kc = 0; kc < 4; kc++) {
        const float* mp = &msgf[(rbase + lc) * MP + kc * 32 + quad * 8];
        f32x4 v0 = *(const f32x4*)mp;
        f32x4 v1 = *(const f32x4*)(mp + 4);
        bf16x8 a;
        a[0] = (short)f2bf(v0.x); a[1] = (short)f2bf(v0.y);
        a[2] = (short)f2bf(v0.z); a[3] = (short)f2bf(v0.w);
        a[4] = (short)f2bf(v1.x); a[5] = (short)f2bf(v1.y);
        a[6] = (short)f2bf(v1.z); a[7] = (short)f2bf(v1.w);
        af[kc] = a;
    }

    const unsigned short* WG = wbih + (size_t)gi * 49152;
    float* hfout = out + (size_t)NN * HD;
    for (int nt = 0; nt < 8; nt++) {
        f32x4 aR = {0.f, 0.f, 0.f, 0.f};
        f32x4 aZ = {0.f, 0.f, 0.f, 0.f};
        f32x4 aN = {0.f, 0.f, 0.f, 0.f};
#pragma unroll
        for (int kc = 0; kc < 4; kc++) {
            bf16x8 bR = *(const bf16x8*)&WG[(((nt)      * 4 + kc) * 64 + ln) * 8];
            bf16x8 bZ = *(const bf16x8*)&WG[(((nt + 8)  * 4 + kc) * 64 + ln) * 8];
            bf16x8 bN = *(const bf16x8*)&WG[(((nt + 16) * 4 + kc) * 64 + ln) * 8];
            aR = __builtin_amdgcn_mfma_f32_16x16x32_bf16(af[kc], bR, aR, 0, 0, 0);
            aZ = __builtin_amdgcn_mfma_f32_16x16x32_bf16(af[kc], bZ, aZ, 0, 0, 0);
            aN = __builtin_amdgcn_mfma_f32_16x16x32_bf16(af[kc], bN, aN, 0, 0, 0);
        }
        int c = nt * 16 + lc;
        float biR = bih[gi * 384 + c],       bhR = bhh[gi * 384 + c];
        float biZ = bih[gi * 384 + 128 + c], bhZ = bhh[gi * 384 + 128 + c];
        float biN = bih[gi * 384 + 256 + c], bhN = bhh[gi * 384 + 256 + c];
#pragma unroll
        for (int r = 0; r < 4; r++) {
            int row = rbase + quad * 4 + r;
            int n = __shfl(nd, quad * 4 + r);
            if (n >= 0 && row < nv) {
                float ir = aR[r] + biR + bhR;
                float iz = aZ[r] + biZ + bhZ;
                float inn = aN[r] + biN;
                float rg = 1.f / (1.f + expf(-ir));
                float zg = 1.f / (1.f + expf(-iz));
                float nst = tanhf(inn + rg * bhN);
                hfout[(size_t)n * HD + c] = (1.f - zg) * nst;
            }
        }
    }
}

extern "C" void kernel_launch(void* const* d_in, const int* in_sizes, int n_in,
                              void* d_out, int out_size, void* d_ws, size_t ws_size,
                              hipStream_t stream) {
    const int* gate = (const int*)d_in[0];
    const int* lvl  = (const int*)d_in[1];
    const int* ei   = (const int*)d_in[2];
    const float* Ws   = (const float*)d_in[3];
    const float* Wt   = (const float*)d_in[4];
    const float* hs_W = (const float*)d_in[5];
    const float* hs_b = (const float*)d_in[6];
    const float* w1 = (const float*)d_in[7];
    const float* b1 = (const float*)d_in[8];
    const float* w2 = (const float*)d_in[9];
    const float* b2 = (const float*)d_in[10];
    const float* w3 = (const float*)d_in[11];
    const float* b3 = (const float*)d_in[12];
    const float* wih = (const float*)d_in[13];
    // d_in[14] = gru_whh: unused (h_old provably zero for every updated node)
    const float* bih = (const float*)d_in[15];
    const float* bhh = (const float*)d_in[16];
    float* out = (float*)d_out;
    char* ws = (char*)d_ws;

    int*   ncnt    = (int*)(ws + OFF_NCNT);
    int*   becnt   = (int*)(ws + OFF_BECNT);
    int*   zcnt    = (int*)(ws + OFF_ZCNT);
    float* hs_type = (float*)(ws + OFF_HSTYPE);
    float* hsW1    = (float*)(ws + OFF_HSW1);
    float* ztab    = (float*)(ws + OFF_ZTAB);
    unsigned short* wbmlp = (unsigned short*)(ws + OFF_WBMLP);
    unsigned short* wbih  = (unsigned short*)(ws + OFF_WBIH);
    int*   nlist   = (int*)(ws + OFF_NLIST);
    int*   nslot   = (int*)(ws + OFF_NSLOT);
    int*   epk     = (int*)(ws + OFF_EPK);

    hipMemsetAsync(ws, 0, MEMSET_BYTES, stream);

    prep1_kernel<<<256, NTHR, 0, stream>>>(gate, lvl, Ws, Wt, hs_W, hs_b,
                                           w1, b1, w2, b2, w3, b3, wih,
                                           hs_type, hsW1, ztab, wbmlp, wbih,
                                           ncnt, nlist, nslot);
    prep2_kernel<<<1024, NTHR, 0, stream>>>(gate, lvl, ei, nslot, hs_type, out,
                                            becnt, epk, zcnt);

    const float* hf = out + (size_t)NN * HD;
    for (int l = 1; l < 8; l++) {
        level_kernel<<<3 * 64, NTHR, 0, stream>>>(l, ncnt, nlist, becnt, epk,
                                                  zcnt, ztab, hf, wbmlp, wbih,
                                                  b1, b2, b3, hsW1, bih, bhh, out);
    }
}